// Round 5
// baseline (1112.635 us; speedup 1.0000x reference)
//
#include <hip/hip_runtime.h>
#include <hip/hip_bf16.h>
#include <math.h>

#define B_  256
#define S_  200
#define F_  10
#define T_  100
#define E_  128
#define H_  256
#define G4  1024   // 4*H
#define P1_ 512
#define P2_ 128

typedef __attribute__((ext_vector_type(8))) short short8;
typedef __attribute__((ext_vector_type(4))) float f32x4;

__device__ __forceinline__ float sigf(float x) { return 1.0f / (1.0f + expf(-x)); }
__device__ __forceinline__ ushort f2bf(float f) {
    __hip_bfloat16 v = __float2bfloat16(f);
    return *(ushort*)&v;
}

__global__ __launch_bounds__(256) void k_bsum(const float* __restrict__ bi,
                                              const float* __restrict__ bh,
                                              float* __restrict__ bs) {
    int i = blockIdx.x * 256 + threadIdx.x;
    if (i < G4) bs[i] = bi[i] + bh[i];
}

// W (R x C) f32 -> WT (C x R) bf16. grid (C/32, R/32), 256 thr.
__global__ __launch_bounds__(256) void k_tr_bf16(const float* __restrict__ W,
                                                 ushort* __restrict__ WT,
                                                 int R, int C) {
    __shared__ float t[32][33];
    int c0 = blockIdx.x * 32, r0 = blockIdx.y * 32;
    int lc = threadIdx.x & 31, lr = threadIdx.x >> 5;
    #pragma unroll
    for (int i = 0; i < 4; ++i)
        t[lr + 8 * i][lc] = W[(long)(r0 + lr + 8 * i) * C + c0 + lc];
    __syncthreads();
    #pragma unroll
    for (int i = 0; i < 4; ++i)
        WT[(long)(c0 + lr + 8 * i) * R + r0 + lc] = f2bf(t[lc][lr + 8 * i]);
}

__global__ __launch_bounds__(256) void k_cvt_bf16(const float* __restrict__ W,
                                                  ushort* __restrict__ O, int n) {
    int i = blockIdx.x * 256 + threadIdx.x;
    if (i < n) O[i] = f2bf(W[i]);
}

// one block per (b,s); 128 threads = one e-dim each; bf16 out
__global__ __launch_bounds__(128) void k_gather(const int* __restrict__ x,
                                                const float* __restrict__ emb,
                                                ushort* __restrict__ e) {
    int bs = blockIdx.x;
    int t  = threadIdx.x;
    const int* xr = x + (long)bs * F_;
    float acc = 0.f;
    #pragma unroll
    for (int f = 0; f < F_; ++f) acc += emb[(long)xr[f] * E_ + t];
    e[(long)bs * E_ + t] = f2bf(acc * (1.0f / F_));
}

// ---------------- bf16 MFMA GEMM (unchanged from r4) ----------------
template<int ACT, int OUTBF>
__global__ __launch_bounds__(256) void k_gemm_mfma(
    const ushort* __restrict__ A, int rowDiv, long sOuter, long sInner,
    const ushort* __restrict__ Bm,
    const float* __restrict__ bias,
    const float* __restrict__ rowAdd, int rowAddDiv,
    void* __restrict__ Cout, int N, int K)
{
    constexpr int LDT = 40;
    __shared__ ushort Al[128 * LDT];
    __shared__ ushort Bl[128 * LDT];
    int tid = threadIdx.x;
    int n0 = blockIdx.x * 128;
    int m0 = blockIdx.y * 128;

    int rA = tid >> 2, qA = tid & 3;
    int m_lo = m0 + rA, m_hi = m_lo + 64;
    long a0 = (long)(m_lo / rowDiv) * sOuter + (long)(m_lo % rowDiv) * sInner + qA * 8;
    long a1 = (long)(m_hi / rowDiv) * sOuter + (long)(m_hi % rowDiv) * sInner + qA * 8;
    const ushort* b0p = Bm + (long)(n0 + rA) * K + qA * 8;
    const ushort* b1p = Bm + (long)(n0 + rA + 64) * K + qA * 8;

    int lane = tid & 63, wave = tid >> 6;
    int wr = wave >> 1, wc = wave & 1;
    int lrow = lane & 15, lkh = lane >> 4;

    const f32x4 fz = {0.f, 0.f, 0.f, 0.f};
    f32x4 acc[4][4];
    #pragma unroll
    for (int i = 0; i < 4; ++i)
        #pragma unroll
        for (int j = 0; j < 4; ++j) acc[i][j] = fz;

    int nk = K >> 5;
    for (int kc = 0; kc < nk; ++kc) {
        uint4 va0 = *(const uint4*)(A + a0 + kc * 32);
        uint4 va1 = *(const uint4*)(A + a1 + kc * 32);
        uint4 vb0 = *(const uint4*)(b0p + kc * 32);
        uint4 vb1 = *(const uint4*)(b1p + kc * 32);
        *(uint4*)&Al[rA * LDT + qA * 8]        = va0;
        *(uint4*)&Al[(rA + 64) * LDT + qA * 8] = va1;
        *(uint4*)&Bl[rA * LDT + qA * 8]        = vb0;
        *(uint4*)&Bl[(rA + 64) * LDT + qA * 8] = vb1;
        __syncthreads();
        short8 af[4], bfr[4];
        #pragma unroll
        for (int mi = 0; mi < 4; ++mi)
            af[mi] = *(const short8*)&Al[(wr * 64 + mi * 16 + lrow) * LDT + lkh * 8];
        #pragma unroll
        for (int ni = 0; ni < 4; ++ni)
            bfr[ni] = *(const short8*)&Bl[(wc * 64 + ni * 16 + lrow) * LDT + lkh * 8];
        #pragma unroll
        for (int mi = 0; mi < 4; ++mi)
            #pragma unroll
            for (int ni = 0; ni < 4; ++ni)
                acc[mi][ni] = __builtin_amdgcn_mfma_f32_16x16x32_bf16(
                    af[mi], bfr[ni], acc[mi][ni], 0, 0, 0);
        __syncthreads();
    }
    #pragma unroll
    for (int mi = 0; mi < 4; ++mi) {
        #pragma unroll
        for (int r = 0; r < 4; ++r) {
            int m = m0 + wr * 64 + mi * 16 + lkh * 4 + r;
            long rowoff = rowAdd ? (long)(m / rowAddDiv) * N : 0;
            #pragma unroll
            for (int ni = 0; ni < 4; ++ni) {
                int n = n0 + wc * 64 + ni * 16 + lrow;
                float v = acc[mi][ni][r];
                if (bias)   v += bias[n];
                if (rowAdd) v += rowAdd[rowoff + n];
                if (ACT)    v = fmaxf(v, 0.f);
                if (OUTBF) ((ushort*)Cout)[(long)m * N + n] = f2bf(v);
                else       ((float*)Cout)[(long)m * N + n] = v;
            }
        }
    }
}

// ---------------- fp32 GEMM (kept for small hhdec) ----------------
template<int BT, int ACT>
__global__ __launch_bounds__(256) void k_gemm(
    const float* __restrict__ A, int rowDiv, long sOuter, long sInner,
    const float* __restrict__ Bm,
    const float* __restrict__ bias,
    const float* __restrict__ rowAdd, int rowAddDiv,
    float* __restrict__ C, int M, int N, int K)
{
    __shared__ float Al[32 * 66];
    __shared__ float Bl[32 * 130];
    int tid = threadIdx.x;
    int n0 = blockIdx.x * 128;
    int m0 = blockIdx.y * 64;
    int cA = tid & 31;
    int rA = tid >> 5;
    long rb[8];
    #pragma unroll
    for (int i = 0; i < 8; ++i) {
        int m = m0 + rA + 8 * i;
        rb[i] = (long)(m / rowDiv) * sOuter + (long)(m % rowDiv) * sInner;
    }
    int tr = tid >> 5, tc = tid & 31;
    float acc[8][4] = {};
    int nk = K >> 5;
    for (int kc = 0; kc < nk; ++kc) {
        #pragma unroll
        for (int i = 0; i < 8; ++i)
            Al[cA * 66 + rA + 8 * i] = A[rb[i] + kc * 32 + cA];
        if (BT) {
            #pragma unroll
            for (int i = 0; i < 16; ++i) {
                int lin = tid + 256 * i;
                int n = lin >> 5, k = lin & 31;
                Bl[k * 130 + n] = Bm[(long)(n0 + n) * K + kc * 32 + k];
            }
        } else {
            #pragma unroll
            for (int i = 0; i < 16; ++i) {
                int lin = tid + 256 * i;
                int k = lin >> 7, n = lin & 127;
                Bl[k * 130 + n] = Bm[(long)(kc * 32 + k) * N + n0 + n];
            }
        }
        __syncthreads();
        #pragma unroll 4
        for (int k = 0; k < 32; ++k) {
            float a_[8], b_[4];
            *(float2*)&a_[0] = *(float2*)&Al[k * 66 + tr * 8];
            *(float2*)&a_[2] = *(float2*)&Al[k * 66 + tr * 8 + 2];
            *(float2*)&a_[4] = *(float2*)&Al[k * 66 + tr * 8 + 4];
            *(float2*)&a_[6] = *(float2*)&Al[k * 66 + tr * 8 + 6];
            *(float2*)&b_[0] = *(float2*)&Bl[k * 130 + tc * 4];
            *(float2*)&b_[2] = *(float2*)&Bl[k * 130 + tc * 4 + 2];
            #pragma unroll
            for (int i = 0; i < 8; ++i)
                #pragma unroll
                for (int j = 0; j < 4; ++j)
                    acc[i][j] += a_[i] * b_[j];
        }
        __syncthreads();
    }
    #pragma unroll
    for (int i = 0; i < 8; ++i) {
        int m = m0 + tr * 8 + i;
        int n = n0 + tc * 4;
        float4 v;
        float* vp = &v.x;
        #pragma unroll
        for (int j = 0; j < 4; ++j) {
            float t = acc[i][j];
            if (bias)   t += bias[n + j];
            if (rowAdd) t += rowAdd[(long)(m / rowAddDiv) * N + n + j];
            if (ACT == 1) t = fmaxf(t, 0.f);
            vp[j] = t;
        }
        *(float4*)&C[(long)m * N + n] = v;
    }
}

// ---------------- cooperative persistent LSTM scan ----------------
// 256 blocks = 16 b-tiles (bt = blockIdx&15, 16 batch rows) x 16 j-slices
// (js = blockIdx>>4, 16 h-cols -> 64 gate-cols). W panel (256k x 64n bf16)
// resident in LDS for all T steps. h exchanged via global bf16 double buffer,
// guarded by per-(bt,t) release/acquire flag counters (intra-group only).
__global__ __launch_bounds__(256) void k_lstm_scan_coop(
    const float* __restrict__ Xg, const ushort* __restrict__ WTb,
    ushort* __restrict__ hbuf,          // [2][256][256] bf16
    int* __restrict__ flags,            // [16][128]
    float* __restrict__ hN, float* __restrict__ cN)
{
    constexpr int WS = 264;             // 256 k + 8 pad (bf16 units)
    __shared__ ushort Wl[64 * WS];      // [n_local][k]
    __shared__ float  gl[16 * 68];      // [b_local][n_local = gate*16+jl]
    int tid = threadIdx.x;
    int bt  = blockIdx.x & 15;
    int js  = blockIdx.x >> 4;
    int b0  = bt * 16;
    int j0  = js * 16;

    // one-time W panel load: n -> gcol = (n>>4)*256 + j0 + (n&15)
    #pragma unroll 4
    for (int i = 0; i < 64; ++i) {
        int idx = tid + 256 * i;
        int k = idx >> 6, n = idx & 63;
        Wl[n * WS + k] = WTb[(long)k * G4 + ((n >> 4) * 256 + j0 + (n & 15))];
    }
    __syncthreads();

    int lane = tid & 63, wave = tid >> 6;
    int lrow = lane & 15, lkh = lane >> 4;
    int bl = tid >> 4, jl = tid & 15;          // cell ownership (16x16)
    const ushort* wrow = &Wl[(wave * 16 + lrow) * WS + lkh * 8];
    float c_r = 0.f, h_val = 0.f;
    const f32x4 fz = {0.f, 0.f, 0.f, 0.f};

    for (int t = 0; t < T_; ++t) {
        f32x4 acc = fz;
        if (t > 0) {
            if (tid == 0) {
                while (__hip_atomic_load(&flags[bt * 128 + t], __ATOMIC_ACQUIRE,
                                         __HIP_MEMORY_SCOPE_AGENT) < 16)
                    __builtin_amdgcn_s_sleep(1);
            }
            __syncthreads();
            const ushort* hrow = hbuf + ((long)(t & 1) * 256 + b0 + lrow) * H_ + lkh * 8;
            #pragma unroll
            for (int kk = 0; kk < 8; ++kk) {
                short8 a = *(const short8*)(hrow + kk * 32);
                short8 b = *(const short8*)(wrow + kk * 32);
                acc = __builtin_amdgcn_mfma_f32_16x16x32_bf16(a, b, acc, 0, 0, 0);
            }
        }
        #pragma unroll
        for (int r = 0; r < 4; ++r)
            gl[(lkh * 4 + r) * 68 + wave * 16 + lrow] = acc[r];
        __syncthreads();
        {
            long xoff = ((long)(b0 + bl) * T_ + t) * G4 + j0 + jl;
            float gi = gl[bl * 68 +  0 + jl] + Xg[xoff];
            float gf = gl[bl * 68 + 16 + jl] + Xg[xoff + 256];
            float gg = gl[bl * 68 + 32 + jl] + Xg[xoff + 512];
            float go = gl[bl * 68 + 48 + jl] + Xg[xoff + 768];
            float cn = sigf(gf) * c_r + sigf(gi) * tanhf(gg);
            c_r = cn;
            h_val = sigf(go) * tanhf(cn);
            if (t < T_ - 1)
                hbuf[((long)((t + 1) & 1) * 256 + b0 + bl) * H_ + j0 + jl] = f2bf(h_val);
        }
        __syncthreads();   // h stores drained (barrier drains vmcnt); gl reads done
        if (t < T_ - 1 && tid == 0)
            __hip_atomic_fetch_add(&flags[bt * 128 + t + 1], 1, __ATOMIC_RELEASE,
                                   __HIP_MEMORY_SCOPE_AGENT);
    }
    hN[(long)(b0 + bl) * H_ + j0 + jl] = h_val;
    cN[(long)(b0 + bl) * H_ + j0 + jl] = c_r;
}

__global__ __launch_bounds__(256) void k_dec_cell(const float* __restrict__ G,
                                                  const float* __restrict__ cNb,
                                                  ushort* __restrict__ hdec) {
    long idx = (long)blockIdx.x * 256 + threadIdx.x;
    int m = (int)(idx >> 8);
    int j = (int)(idx & 255);
    int b = m / T_;
    const float* g = G + (long)m * G4 + j;
    float gi = g[0], gf = g[H_], gg = g[2 * H_], go = g[3 * H_];
    float cv = sigf(gf) * cNb[(long)b * H_ + j] + sigf(gi) * tanhf(gg);
    hdec[idx] = f2bf(sigf(go) * tanhf(cv));
}

__global__ __launch_bounds__(256) void k_mlp3(const float* __restrict__ z2,
                                              const float* __restrict__ W3,
                                              const float* __restrict__ b3,
                                              float* __restrict__ out) {
    int wave = threadIdx.x >> 6, lane = threadIdx.x & 63;
    int m = blockIdx.x * 4 + wave;
    const float* zr = z2 + (long)m * P2_;
    float s = zr[lane] * W3[lane] + zr[64 + lane] * W3[64 + lane];
    #pragma unroll
    for (int off = 32; off > 0; off >>= 1) s += __shfl_down(s, off);
    if (lane == 0) out[m] = sigf(s + b3[0]);
}

extern "C" void kernel_launch(void* const* d_in, const int* in_sizes, int n_in,
                              void* d_out, int out_size, void* d_ws, size_t ws_size,
                              hipStream_t stream)
{
    const int*   x    = (const int*)d_in[0];
    const float* emb  = (const float*)d_in[1];
    const float* W_ih = (const float*)d_in[2];
    const float* W_hh = (const float*)d_in[3];
    const float* b_ih = (const float*)d_in[4];
    const float* b_hh = (const float*)d_in[5];
    const float* W1   = (const float*)d_in[6];
    const float* b1   = (const float*)d_in[7];
    const float* W2   = (const float*)d_in[8];
    const float* b2   = (const float*)d_in[9];
    const float* W3   = (const float*)d_in[10];
    const float* b3   = (const float*)d_in[11];
    float* out = (float*)d_out;

    float* ws = (float*)d_ws;
    ushort* ebf  = (ushort*)ws;                 // B*S*E bf16 (3,276,800 f)
    float* Xg    = ws + 3276800;                // 26,214,400 f
    float* bsum  = Xg + 26214400;               // 1024
    float* hN    = bsum + 1024;                 // 65,536
    float* cN    = hN + 65536;                  // 65,536
    float* hhdec = cN + 65536;                  // 262,144
    ushort* WTb  = (ushort*)(hhdec + 262144);   // 262,144 ush (131,072 f)
    ushort* Wihb = WTb + 262144;                // 131,072 ush (65,536 f)
    ushort* W1T  = Wihb + 131072;               // 131,072 ush (65,536 f)
    ushort* W2T  = W1T + 131072;                // 65,536 ush  (32,768 f)
    ushort* hbuf = W2T + 65536;                 // 131,072 ush (65,536 f)
    int*   flags = (int*)(hbuf + 131072);       // 2048 ints
    // reuse (stream-ordered):
    ushort* hdec_bf = ebf;
    ushort* z1b  = (ushort*)Xg;
    float*  z2   = Xg + 6553600;

    hipMemsetAsync(flags, 0, 16 * 128 * sizeof(int), stream);

    k_bsum<<<4, 256, 0, stream>>>(b_ih, b_hh, bsum);
    k_tr_bf16<<<dim3(8, 32),  256, 0, stream>>>(W_hh, WTb, G4, H_);
    k_tr_bf16<<<dim3(16, 8),  256, 0, stream>>>(W1, W1T, H_, P1_);
    k_tr_bf16<<<dim3(4, 16),  256, 0, stream>>>(W2, W2T, P1_, P2_);
    k_cvt_bf16<<<512, 256, 0, stream>>>(W_ih, Wihb, G4 * E_);
    k_gather<<<B_ * S_, 128, 0, stream>>>(x, emb, ebf);

    // Xg = e_hist @ W_ih^T + bsum
    k_gemm_mfma<0, 0><<<dim3(G4 / 128, (B_ * T_) / 128), 256, 0, stream>>>(
        ebf, T_, (long)S_ * E_, (long)E_, Wihb, bsum, nullptr, 1,
        Xg, G4, E_);

    // cooperative persistent scan
    k_lstm_scan_coop<<<256, 256, 0, stream>>>(Xg, WTb, hbuf, flags, hN, cN);

    // hhdec = hN @ W_hh^T + bsum (fp32, tiny)
    k_gemm<1, 0><<<dim3(G4 / 128, B_ / 64), 256, 0, stream>>>(
        hN, B_, 0L, (long)H_, W_hh, bsum, nullptr, 1,
        hhdec, B_, G4, H_);

    // Gdec = e_tgt @ W_ih^T + hhdec[b]
    k_gemm_mfma<0, 0><<<dim3(G4 / 128, (B_ * T_) / 128), 256, 0, stream>>>(
        ebf + T_ * E_, T_, (long)S_ * E_, (long)E_, Wihb, nullptr, hhdec, T_,
        Xg, G4, E_);

    // decode cell -> hdec_bf
    k_dec_cell<<<(B_ * T_ * H_) / 256, 256, 0, stream>>>(Xg, cN, hdec_bf);

    // z1 = relu(hdec @ W1 + b1) -> bf16
    k_gemm_mfma<1, 1><<<dim3(P1_ / 128, (B_ * T_) / 128), 256, 0, stream>>>(
        hdec_bf, B_ * T_, 0L, (long)H_, W1T, b1, nullptr, 1,
        z1b, P1_, H_);

    // z2 = relu(z1 @ W2 + b2) -> f32
    k_gemm_mfma<1, 0><<<dim3(P2_ / 128, (B_ * T_) / 128), 256, 0, stream>>>(
        z1b, B_ * T_, 0L, (long)P1_, W2T, b2, nullptr, 1,
        z2, P2_, P1_);

    // out = sigmoid(z2 . W3 + b3)
    k_mlp3<<<(B_ * T_) / 4, 256, 0, stream>>>(z2, W3, b3, out);
}

// Round 6
// 789.097 us; speedup vs baseline: 1.4100x; 1.4100x over previous
//
#include <hip/hip_runtime.h>
#include <hip/hip_bf16.h>
#include <math.h>

#define B_  256
#define S_  200
#define F_  10
#define T_  100
#define E_  128
#define H_  256
#define G4  1024   // 4*H
#define P1_ 512
#define P2_ 128

typedef __attribute__((ext_vector_type(8))) short short8;
typedef __attribute__((ext_vector_type(4))) float f32x4;
typedef _Float16 half8f __attribute__((ext_vector_type(8)));

__device__ __forceinline__ float sigf(float x) { return 1.0f / (1.0f + expf(-x)); }
__device__ __forceinline__ ushort f2bf(float f) {
    __hip_bfloat16 v = __float2bfloat16(f);
    return *(ushort*)&v;
}
__device__ __forceinline__ ushort f2h(float f) {
    _Float16 h = (_Float16)f;
    return __builtin_bit_cast(ushort, h);
}

__global__ __launch_bounds__(256) void k_bsum(const float* __restrict__ bi,
                                              const float* __restrict__ bh,
                                              float* __restrict__ bs) {
    int i = blockIdx.x * 256 + threadIdx.x;
    if (i < G4) bs[i] = bi[i] + bh[i];
}

// W (R x C) f32 -> WT (C x R) bf16. grid (C/32, R/32), 256 thr.
__global__ __launch_bounds__(256) void k_tr_bf16(const float* __restrict__ W,
                                                 ushort* __restrict__ WT,
                                                 int R, int C) {
    __shared__ float t[32][33];
    int c0 = blockIdx.x * 32, r0 = blockIdx.y * 32;
    int lc = threadIdx.x & 31, lr = threadIdx.x >> 5;
    #pragma unroll
    for (int i = 0; i < 4; ++i)
        t[lr + 8 * i][lc] = W[(long)(r0 + lr + 8 * i) * C + c0 + lc];
    __syncthreads();
    #pragma unroll
    for (int i = 0; i < 4; ++i)
        WT[(long)(c0 + lr + 8 * i) * R + r0 + lc] = f2bf(t[lc][lr + 8 * i]);
}

// W (R x C) f32 -> WT (C x R) fp16 (for the scan's fma_mix path)
__global__ __launch_bounds__(256) void k_tr_f16(const float* __restrict__ W,
                                                ushort* __restrict__ WT,
                                                int R, int C) {
    __shared__ float t[32][33];
    int c0 = blockIdx.x * 32, r0 = blockIdx.y * 32;
    int lc = threadIdx.x & 31, lr = threadIdx.x >> 5;
    #pragma unroll
    for (int i = 0; i < 4; ++i)
        t[lr + 8 * i][lc] = W[(long)(r0 + lr + 8 * i) * C + c0 + lc];
    __syncthreads();
    #pragma unroll
    for (int i = 0; i < 4; ++i)
        WT[(long)(c0 + lr + 8 * i) * R + r0 + lc] = f2h(t[lc][lr + 8 * i]);
}

__global__ __launch_bounds__(256) void k_cvt_bf16(const float* __restrict__ W,
                                                  ushort* __restrict__ O, int n) {
    int i = blockIdx.x * 256 + threadIdx.x;
    if (i < n) O[i] = f2bf(W[i]);
}

// one block per (b,s); 128 threads = one e-dim each; bf16 out
__global__ __launch_bounds__(128) void k_gather(const int* __restrict__ x,
                                                const float* __restrict__ emb,
                                                ushort* __restrict__ e) {
    int bs = blockIdx.x;
    int t  = threadIdx.x;
    const int* xr = x + (long)bs * F_;
    float acc = 0.f;
    #pragma unroll
    for (int f = 0; f < F_; ++f) acc += emb[(long)xr[f] * E_ + t];
    e[(long)bs * E_ + t] = f2bf(acc * (1.0f / F_));
}

// ---------------- bf16 MFMA GEMM (unchanged) ----------------
template<int ACT, int OUTBF>
__global__ __launch_bounds__(256) void k_gemm_mfma(
    const ushort* __restrict__ A, int rowDiv, long sOuter, long sInner,
    const ushort* __restrict__ Bm,
    const float* __restrict__ bias,
    const float* __restrict__ rowAdd, int rowAddDiv,
    void* __restrict__ Cout, int N, int K)
{
    constexpr int LDT = 40;
    __shared__ ushort Al[128 * LDT];
    __shared__ ushort Bl[128 * LDT];
    int tid = threadIdx.x;
    int n0 = blockIdx.x * 128;
    int m0 = blockIdx.y * 128;

    int rA = tid >> 2, qA = tid & 3;
    int m_lo = m0 + rA, m_hi = m_lo + 64;
    long a0 = (long)(m_lo / rowDiv) * sOuter + (long)(m_lo % rowDiv) * sInner + qA * 8;
    long a1 = (long)(m_hi / rowDiv) * sOuter + (long)(m_hi % rowDiv) * sInner + qA * 8;
    const ushort* b0p = Bm + (long)(n0 + rA) * K + qA * 8;
    const ushort* b1p = Bm + (long)(n0 + rA + 64) * K + qA * 8;

    int lane = tid & 63, wave = tid >> 6;
    int wr = wave >> 1, wc = wave & 1;
    int lrow = lane & 15, lkh = lane >> 4;

    const f32x4 fz = {0.f, 0.f, 0.f, 0.f};
    f32x4 acc[4][4];
    #pragma unroll
    for (int i = 0; i < 4; ++i)
        #pragma unroll
        for (int j = 0; j < 4; ++j) acc[i][j] = fz;

    int nk = K >> 5;
    for (int kc = 0; kc < nk; ++kc) {
        uint4 va0 = *(const uint4*)(A + a0 + kc * 32);
        uint4 va1 = *(const uint4*)(A + a1 + kc * 32);
        uint4 vb0 = *(const uint4*)(b0p + kc * 32);
        uint4 vb1 = *(const uint4*)(b1p + kc * 32);
        *(uint4*)&Al[rA * LDT + qA * 8]        = va0;
        *(uint4*)&Al[(rA + 64) * LDT + qA * 8] = va1;
        *(uint4*)&Bl[rA * LDT + qA * 8]        = vb0;
        *(uint4*)&Bl[(rA + 64) * LDT + qA * 8] = vb1;
        __syncthreads();
        short8 af[4], bfr[4];
        #pragma unroll
        for (int mi = 0; mi < 4; ++mi)
            af[mi] = *(const short8*)&Al[(wr * 64 + mi * 16 + lrow) * LDT + lkh * 8];
        #pragma unroll
        for (int ni = 0; ni < 4; ++ni)
            bfr[ni] = *(const short8*)&Bl[(wc * 64 + ni * 16 + lrow) * LDT + lkh * 8];
        #pragma unroll
        for (int mi = 0; mi < 4; ++mi)
            #pragma unroll
            for (int ni = 0; ni < 4; ++ni)
                acc[mi][ni] = __builtin_amdgcn_mfma_f32_16x16x32_bf16(
                    af[mi], bfr[ni], acc[mi][ni], 0, 0, 0);
        __syncthreads();
    }
    #pragma unroll
    for (int mi = 0; mi < 4; ++mi) {
        #pragma unroll
        for (int r = 0; r < 4; ++r) {
            int m = m0 + wr * 64 + mi * 16 + lkh * 4 + r;
            long rowoff = rowAdd ? (long)(m / rowAddDiv) * N : 0;
            #pragma unroll
            for (int ni = 0; ni < 4; ++ni) {
                int n = n0 + wc * 64 + ni * 16 + lrow;
                float v = acc[mi][ni][r];
                if (bias)   v += bias[n];
                if (rowAdd) v += rowAdd[rowoff + n];
                if (ACT)    v = fmaxf(v, 0.f);
                if (OUTBF) ((ushort*)Cout)[(long)m * N + n] = f2bf(v);
                else       ((float*)Cout)[(long)m * N + n] = v;
            }
        }
    }
}

// ---------------- fp32 GEMM (kept for small hhdec) ----------------
template<int BT, int ACT>
__global__ __launch_bounds__(256) void k_gemm(
    const float* __restrict__ A, int rowDiv, long sOuter, long sInner,
    const float* __restrict__ Bm,
    const float* __restrict__ bias,
    const float* __restrict__ rowAdd, int rowAddDiv,
    float* __restrict__ C, int M, int N, int K)
{
    __shared__ float Al[32 * 66];
    __shared__ float Bl[32 * 130];
    int tid = threadIdx.x;
    int n0 = blockIdx.x * 128;
    int m0 = blockIdx.y * 64;
    int cA = tid & 31;
    int rA = tid >> 5;
    long rb[8];
    #pragma unroll
    for (int i = 0; i < 8; ++i) {
        int m = m0 + rA + 8 * i;
        rb[i] = (long)(m / rowDiv) * sOuter + (long)(m % rowDiv) * sInner;
    }
    int tr = tid >> 5, tc = tid & 31;
    float acc[8][4] = {};
    int nk = K >> 5;
    for (int kc = 0; kc < nk; ++kc) {
        #pragma unroll
        for (int i = 0; i < 8; ++i)
            Al[cA * 66 + rA + 8 * i] = A[rb[i] + kc * 32 + cA];
        if (BT) {
            #pragma unroll
            for (int i = 0; i < 16; ++i) {
                int lin = tid + 256 * i;
                int n = lin >> 5, k = lin & 31;
                Bl[k * 130 + n] = Bm[(long)(n0 + n) * K + kc * 32 + k];
            }
        } else {
            #pragma unroll
            for (int i = 0; i < 16; ++i) {
                int lin = tid + 256 * i;
                int k = lin >> 7, n = lin & 127;
                Bl[k * 130 + n] = Bm[(long)(kc * 32 + k) * N + n0 + n];
            }
        }
        __syncthreads();
        #pragma unroll 4
        for (int k = 0; k < 32; ++k) {
            float a_[8], b_[4];
            *(float2*)&a_[0] = *(float2*)&Al[k * 66 + tr * 8];
            *(float2*)&a_[2] = *(float2*)&Al[k * 66 + tr * 8 + 2];
            *(float2*)&a_[4] = *(float2*)&Al[k * 66 + tr * 8 + 4];
            *(float2*)&a_[6] = *(float2*)&Al[k * 66 + tr * 8 + 6];
            *(float2*)&b_[0] = *(float2*)&Bl[k * 130 + tc * 4];
            *(float2*)&b_[2] = *(float2*)&Bl[k * 130 + tc * 4 + 2];
            #pragma unroll
            for (int i = 0; i < 8; ++i)
                #pragma unroll
                for (int j = 0; j < 4; ++j)
                    acc[i][j] += a_[i] * b_[j];
        }
        __syncthreads();
    }
    #pragma unroll
    for (int i = 0; i < 8; ++i) {
        int m = m0 + tr * 8 + i;
        int n = n0 + tc * 4;
        float4 v;
        float* vp = &v.x;
        #pragma unroll
        for (int j = 0; j < 4; ++j) {
            float t = acc[i][j];
            if (bias)   t += bias[n + j];
            if (rowAdd) t += rowAdd[(long)(m / rowAddDiv) * N + n + j];
            if (ACT == 1) t = fmaxf(t, 0.f);
            vp[j] = t;
        }
        *(float4*)&C[(long)m * N + n] = v;
    }
}

// Persistent batch-parallel LSTM scan (r4 broadcast structure), fp16 weights.
// WTh is W_hh transposed to (K=256) x (G=1024), fp16. h stays f32.
// Inner product uses (float)w_half * h_f32 -> v_fma_mix_f32 (f32 accumulate).
__global__ __launch_bounds__(1024) void k_lstm_scan(
    const float* __restrict__ Xg, const ushort* __restrict__ WTh,
    float* __restrict__ hN, float* __restrict__ cN)
{
    __shared__ __align__(16) float h_s[H_];
    __shared__ __align__(16) float red[8 * G4];
    __shared__ __align__(16) float act_s[G4];
    int tid = threadIdx.x;
    int b   = blockIdx.x;
    int kg  = tid >> 7;          // k-group 0..7
    int go  = (tid & 127) * 8;   // gate-octet base
    float c_r = 0.f;
    if (tid < H_) h_s[tid] = 0.f;
    __syncthreads();
    const float* xgb = Xg + (long)b * T_ * G4;
    const ushort* wq = WTh + (long)(kg * 32) * G4 + go;
    for (int t = 0; t < T_; ++t) {
        float a0 = 0.f, a1 = 0.f, a2 = 0.f, a3 = 0.f;
        float a4 = 0.f, a5 = 0.f, a6 = 0.f, a7 = 0.f;
        #pragma unroll 8
        for (int i = 0; i < 32; ++i) {
            half8f w = *(const half8f*)(wq + (long)i * G4);
            float hv = h_s[kg * 32 + i];
            a0 += (float)w[0] * hv; a1 += (float)w[1] * hv;
            a2 += (float)w[2] * hv; a3 += (float)w[3] * hv;
            a4 += (float)w[4] * hv; a5 += (float)w[5] * hv;
            a6 += (float)w[6] * hv; a7 += (float)w[7] * hv;
        }
        *(float4*)&red[kg * G4 + go]     = make_float4(a0, a1, a2, a3);
        *(float4*)&red[kg * G4 + go + 4] = make_float4(a4, a5, a6, a7);
        __syncthreads();
        float g = red[tid] + red[G4 + tid] + red[2 * G4 + tid] + red[3 * G4 + tid]
                + red[4 * G4 + tid] + red[5 * G4 + tid] + red[6 * G4 + tid] + red[7 * G4 + tid]
                + xgb[(long)t * G4 + tid];
        act_s[tid] = ((tid >> 8) == 2) ? tanhf(g) : sigf(g);
        __syncthreads();
        if (tid < H_) {
            float cn = act_s[H_ + tid] * c_r + act_s[tid] * act_s[2 * H_ + tid];
            c_r = cn;
            h_s[tid] = act_s[3 * H_ + tid] * tanhf(cn);
        }
        __syncthreads();
    }
    if (tid < H_) {
        hN[(long)b * H_ + tid] = h_s[tid];
        cN[(long)b * H_ + tid] = c_r;
    }
}

__global__ __launch_bounds__(256) void k_dec_cell(const float* __restrict__ G,
                                                  const float* __restrict__ cNb,
                                                  ushort* __restrict__ hdec) {
    long idx = (long)blockIdx.x * 256 + threadIdx.x;
    int m = (int)(idx >> 8);
    int j = (int)(idx & 255);
    int b = m / T_;
    const float* g = G + (long)m * G4 + j;
    float gi = g[0], gf = g[H_], gg = g[2 * H_], go = g[3 * H_];
    float cv = sigf(gf) * cNb[(long)b * H_ + j] + sigf(gi) * tanhf(gg);
    hdec[idx] = f2bf(sigf(go) * tanhf(cv));
}

__global__ __launch_bounds__(256) void k_mlp3(const float* __restrict__ z2,
                                              const float* __restrict__ W3,
                                              const float* __restrict__ b3,
                                              float* __restrict__ out) {
    int wave = threadIdx.x >> 6, lane = threadIdx.x & 63;
    int m = blockIdx.x * 4 + wave;
    const float* zr = z2 + (long)m * P2_;
    float s = zr[lane] * W3[lane] + zr[64 + lane] * W3[64 + lane];
    #pragma unroll
    for (int off = 32; off > 0; off >>= 1) s += __shfl_down(s, off);
    if (lane == 0) out[m] = sigf(s + b3[0]);
}

extern "C" void kernel_launch(void* const* d_in, const int* in_sizes, int n_in,
                              void* d_out, int out_size, void* d_ws, size_t ws_size,
                              hipStream_t stream)
{
    const int*   x    = (const int*)d_in[0];
    const float* emb  = (const float*)d_in[1];
    const float* W_ih = (const float*)d_in[2];
    const float* W_hh = (const float*)d_in[3];
    const float* b_ih = (const float*)d_in[4];
    const float* b_hh = (const float*)d_in[5];
    const float* W1   = (const float*)d_in[6];
    const float* b1   = (const float*)d_in[7];
    const float* W2   = (const float*)d_in[8];
    const float* b2   = (const float*)d_in[9];
    const float* W3   = (const float*)d_in[10];
    const float* b3   = (const float*)d_in[11];
    float* out = (float*)d_out;

    float* ws = (float*)d_ws;
    ushort* ebf  = (ushort*)ws;                 // B*S*E bf16 (3,276,800 f)
    float* Xg    = ws + 3276800;                // 26,214,400 f
    float* bsum  = Xg + 26214400;               // 1024
    float* hN    = bsum + 1024;                 // 65,536
    float* cN    = hN + 65536;                  // 65,536
    float* hhdec = cN + 65536;                  // 262,144
    ushort* WTh  = (ushort*)(hhdec + 262144);   // 262,144 ush (fp16 W_hh^T)
    ushort* Wihb = WTh + 262144;                // 131,072 ush
    ushort* W1T  = Wihb + 131072;               // 131,072 ush
    ushort* W2T  = W1T + 131072;                // 65,536 ush
    // reuse (stream-ordered):
    ushort* hdec_bf = ebf;
    ushort* z1b  = (ushort*)Xg;
    float*  z2   = Xg + 6553600;

    k_bsum<<<4, 256, 0, stream>>>(b_ih, b_hh, bsum);
    k_tr_f16 <<<dim3(8, 32),  256, 0, stream>>>(W_hh, WTh, G4, H_);
    k_tr_bf16<<<dim3(16, 8),  256, 0, stream>>>(W1, W1T, H_, P1_);
    k_tr_bf16<<<dim3(4, 16),  256, 0, stream>>>(W2, W2T, P1_, P2_);
    k_cvt_bf16<<<512, 256, 0, stream>>>(W_ih, Wihb, G4 * E_);
    k_gather<<<B_ * S_, 128, 0, stream>>>(x, emb, ebf);

    // Xg = e_hist @ W_ih^T + bsum
    k_gemm_mfma<0, 0><<<dim3(G4 / 128, (B_ * T_) / 128), 256, 0, stream>>>(
        ebf, T_, (long)S_ * E_, (long)E_, Wihb, bsum, nullptr, 1,
        Xg, G4, E_);

    // persistent broadcast scan (fp16 W, fma_mix)
    k_lstm_scan<<<B_, 1024, 0, stream>>>(Xg, WTh, hN, cN);

    // hhdec = hN @ W_hh^T + bsum (fp32, tiny)
    k_gemm<1, 0><<<dim3(G4 / 128, B_ / 64), 256, 0, stream>>>(
        hN, B_, 0L, (long)H_, W_hh, bsum, nullptr, 1,
        hhdec, B_, G4, H_);

    // Gdec = e_tgt @ W_ih^T + hhdec[b]
    k_gemm_mfma<0, 0><<<dim3(G4 / 128, (B_ * T_) / 128), 256, 0, stream>>>(
        ebf + T_ * E_, T_, (long)S_ * E_, (long)E_, Wihb, nullptr, hhdec, T_,
        Xg, G4, E_);

    // decode cell -> hdec_bf
    k_dec_cell<<<(B_ * T_ * H_) / 256, 256, 0, stream>>>(Xg, cN, hdec_bf);

    // z1 = relu(hdec @ W1 + b1) -> bf16
    k_gemm_mfma<1, 1><<<dim3(P1_ / 128, (B_ * T_) / 128), 256, 0, stream>>>(
        hdec_bf, B_ * T_, 0L, (long)H_, W1T, b1, nullptr, 1,
        z1b, P1_, H_);

    // z2 = relu(z1 @ W2 + b2) -> f32
    k_gemm_mfma<1, 0><<<dim3(P2_ / 128, (B_ * T_) / 128), 256, 0, stream>>>(
        z1b, B_ * T_, 0L, (long)P1_, W2T, b2, nullptr, 1,
        z2, P2_, P1_);

    // out = sigmoid(z2 . W3 + b3)
    k_mlp3<<<(B_ * T_) / 4, 256, 0, stream>>>(z2, W3, b3, out);
}